// Round 8
// baseline (384.729 us; speedup 1.0000x reference)
//
#include <hip/hip_runtime.h>
#include <hip/hip_bf16.h>
#include <stdint.h>

#define IN_F 1024
#define OUT_F 1024
#define NB 8
#define KDIM (IN_F + IN_F * NB)  /* 9216 */
#define NROWS 4096
#define SLICE_ELEMS (NROWS * OUT_F)
#define PREP_BLOCKS ((NROWS * IN_F) / 256)        /* 16384 */
#define WCONV_BLOCKS ((OUT_F * KDIM) / (4 * 256)) /* 9216  */

typedef __attribute__((ext_vector_type(8))) short bf16x8;
typedef __attribute__((ext_vector_type(4))) short bf16x4;
typedef __attribute__((ext_vector_type(4))) float f32x4;

// Closed-form uniform cubic B-spline (knots t_j = -2.2 + 0.4j; EPS=1e-8 shift is
// far below bf16 rounding). For x in [t_i,t_{i+1}): 4 nonzero cardinal cubics.
__device__ __forceinline__ void bspline8(float x, float b8[8]) {
  float u = (x + 2.2f) * 2.5f;  // (x - t0)/h
  bool in = (u >= 0.0f) && (u < 11.0f);
  float uc = fminf(fmaxf(u, 0.0f), 10.99f);
  int i = (int)uc;
  float f = uc - (float)i;
  float g = 1.0f - f;
  float f2 = f * f, f3 = f2 * f;
  const float s = 1.0f / 6.0f;
  float v0 = f3 * s;
  float v1 = (-3.0f * f3 + 3.0f * f2 + 3.0f * f + 1.0f) * s;
  float v2 = (3.0f * f3 - 6.0f * f2 + 4.0f) * s;
  float v3 = g * g * g * s;
#pragma unroll
  for (int j = 0; j < 8; ++j) {
    int d = i - j;
    float r = (d == 0) ? v0 : (d == 1) ? v1 : (d == 2) ? v2 : (d == 3) ? v3 : 0.0f;
    b8[j] = in ? r : 0.0f;
  }
}

// A := [silu(x) | bspline(x)] bf16, W := [bw | sw] bf16. One launch, branch on blockIdx.
__global__ void prep_all_kernel(const float* __restrict__ x, const float* __restrict__ bw,
                                const float* __restrict__ sw, __hip_bfloat16* __restrict__ A,
                                __hip_bfloat16* __restrict__ W) {
  if (blockIdx.x < PREP_BLOCKS) {
    int idx = blockIdx.x * 256 + threadIdx.x;
    int n = idx >> 10;
    int i = idx & 1023;
    float xv = x[idx];
    float sl = xv / (1.0f + __expf(-xv));
    __hip_bfloat16* row = A + (size_t)n * KDIM;
    row[i] = __float2bfloat16(sl);
    float b8[8];
    bspline8(xv, b8);
    alignas(16) __hip_bfloat16 tmp[8];
#pragma unroll
    for (int c = 0; c < 8; ++c) tmp[c] = __float2bfloat16(b8[c]);
    *(bf16x8*)(row + IN_F + i * 8) = *(const bf16x8*)tmp;
  } else {
    int v = (blockIdx.x - PREP_BLOCKS) * 256 + threadIdx.x;
    int e = v * 4;
    int o = e / KDIM;
    int k = e - o * KDIM;
    float4 val = (k < IN_F) ? *(const float4*)(bw + o * IN_F + k)
                            : *(const float4*)(sw + (size_t)o * (IN_F * NB) + (k - IN_F));
    alignas(8) __hip_bfloat16 t[4];
    t[0] = __float2bfloat16(val.x);
    t[1] = __float2bfloat16(val.y);
    t[2] = __float2bfloat16(val.z);
    t[3] = __float2bfloat16(val.w);
    *(bf16x4*)(W + e) = *(const bf16x4*)t;
  }
}

// Barrier-free GEMM: dst = A[4096,9216] @ W[1024,9216]^T (+bias), split-K over z.
// NO LDS, NO __syncthreads in the K-loop. Each wave global_load_dwordx4's its own
// MFMA fragments (the A/B-operand lane map row=l&15, k=(l>>4)*8+j is directly a
// 16-rows x 16B-chunks global pattern), register-double-buffered with prefetch
// distance 1. The compiler emits per-load fine-grained vmcnt waits -- never the
// structural vmcnt(0)-before-s_barrier drain that capped rounds 1-7 (m131-m140:
// that drain is unfixable within the 2-barrier K-loop). Intra-block duplicate
// fragment reads (2 waves share each A/B 64-row set; 8KB/iter) are L1-served.
template <int ITERS>
__global__ __launch_bounds__(256) void gemm_kernel(const __hip_bfloat16* __restrict__ A,
                                                   const __hip_bfloat16* __restrict__ W,
                                                   float* __restrict__ dst,
                                                   const float* __restrict__ bias, int use_bias) {
  const int lane = threadIdx.x & 63;
  const int wave = threadIdx.x >> 6;
  const int bm = blockIdx.x * 128;
  const int bn = blockIdx.y * 128;
  const int kbeg = blockIdx.z * (ITERS * 32);
  const int wm = (wave & 1) * 64;  // 2x2 wave grid, 64x64 per wave
  const int wn = (wave >> 1) * 64;
  const int r = lane & 15;
  const int quad = lane >> 4;

  // Per-lane fragment base pointers (advance by 32 elems per K-step).
  const __hip_bfloat16* pa[4];
  const __hip_bfloat16* pb[4];
#pragma unroll
  for (int t = 0; t < 4; ++t) {
    pa[t] = A + (size_t)(bm + wm + t * 16 + r) * KDIM + kbeg + quad * 8;
    pb[t] = W + (size_t)(bn + wn + t * 16 + r) * KDIM + kbeg + quad * 8;
  }

  f32x4 acc[4][4];
#pragma unroll
  for (int a = 0; a < 4; ++a)
#pragma unroll
    for (int b = 0; b < 4; ++b) acc[a][b] = (f32x4){0.f, 0.f, 0.f, 0.f};

  bf16x8 ca[4], cb[4], na[4], nb[4];
#pragma unroll
  for (int t = 0; t < 4; ++t) {
    ca[t] = *(const bf16x8*)(pa[t]);
    cb[t] = *(const bf16x8*)(pb[t]);
  }

  for (int it = 0; it < ITERS; it += 2) {
    // Prefetch it+1 (always in range: it+1 <= ITERS-1), then MFMA on it.
#pragma unroll
    for (int t = 0; t < 4; ++t) {
      na[t] = *(const bf16x8*)(pa[t] + (it + 1) * 32);
      nb[t] = *(const bf16x8*)(pb[t] + (it + 1) * 32);
    }
#pragma unroll
    for (int tm = 0; tm < 4; ++tm)
#pragma unroll
      for (int tn = 0; tn < 4; ++tn)
        acc[tm][tn] =
            __builtin_amdgcn_mfma_f32_16x16x32_bf16(ca[tm], cb[tn], acc[tm][tn], 0, 0, 0);
    // Prefetch it+2, then MFMA on it+1.
    if (it + 2 < ITERS) {
#pragma unroll
      for (int t = 0; t < 4; ++t) {
        ca[t] = *(const bf16x8*)(pa[t] + (it + 2) * 32);
        cb[t] = *(const bf16x8*)(pb[t] + (it + 2) * 32);
      }
    }
#pragma unroll
    for (int tm = 0; tm < 4; ++tm)
#pragma unroll
      for (int tn = 0; tn < 4; ++tn)
        acc[tm][tn] =
            __builtin_amdgcn_mfma_f32_16x16x32_bf16(na[tm], nb[tn], acc[tm][tn], 0, 0, 0);
  }

  // C/D map: col=lane&15, row=quad*4+reg (m89-verified). Plain stores (no atomics).
  float* __restrict__ d = dst + (size_t)blockIdx.z * SLICE_ELEMS;
#pragma unroll
  for (int tm = 0; tm < 4; ++tm) {
#pragma unroll
    for (int tn = 0; tn < 4; ++tn) {
      const int col = bn + wn + tn * 16 + r;
      const float bv = use_bias ? bias[col] : 0.0f;
#pragma unroll
      for (int reg = 0; reg < 4; ++reg) {
        const int rowi = bm + wm + tm * 16 + quad * 4 + reg;
        d[(size_t)rowi * OUT_F + col] = acc[tm][tn][reg] + bv;
      }
    }
  }
}

// out = bias + sum_s P[s], float4 per thread.
__global__ void reduce_kernel(const float* __restrict__ P, const float* __restrict__ bias,
                              float* __restrict__ out, int S) {
  int v = blockIdx.x * 256 + threadIdx.x;
  int e = v * 4;
  int o = e & (OUT_F - 1);
  float4 acc = *(const float4*)(bias + o);
  for (int s = 0; s < S; ++s) {
    float4 p = *(const float4*)(P + (size_t)s * SLICE_ELEMS + e);
    acc.x += p.x;
    acc.y += p.y;
    acc.z += p.z;
    acc.w += p.w;
  }
  *(float4*)(out + e) = acc;
}

// Emergency fallback if ws is too small for A+W (fp32, slow but correct).
__global__ void kan_fallback(const float* __restrict__ x, const float* __restrict__ bw,
                             const float* __restrict__ bb, const float* __restrict__ sw,
                             float* __restrict__ out) {
  __shared__ float act[KDIM];
  int n = blockIdx.x;
  for (int i = threadIdx.x; i < IN_F; i += 256) {
    float xv = x[(size_t)n * IN_F + i];
    act[i] = xv / (1.0f + __expf(-xv));
    float b8[8];
    bspline8(xv, b8);
#pragma unroll
    for (int c = 0; c < 8; ++c) act[IN_F + i * 8 + c] = b8[c];
  }
  __syncthreads();
  for (int o = threadIdx.x; o < OUT_F; o += 256) {
    float s = bb[o];
    const float* wbp = bw + (size_t)o * IN_F;
    for (int k = 0; k < IN_F; ++k) s += act[k] * wbp[k];
    const float* wsp = sw + (size_t)o * (IN_F * NB);
    for (int k = 0; k < IN_F * NB; ++k) s += act[IN_F + k] * wsp[k];
    out[(size_t)n * OUT_F + o] = s;
  }
}

extern "C" void kernel_launch(void* const* d_in, const int* in_sizes, int n_in, void* d_out,
                              int out_size, void* d_ws, size_t ws_size, hipStream_t stream) {
  const float* x = (const float*)d_in[0];
  const float* bw = (const float*)d_in[1];
  const float* bb = (const float*)d_in[2];
  const float* sw = (const float*)d_in[3];
  float* out = (float*)d_out;

  const size_t needA = (size_t)NROWS * KDIM * 2;  // 75.5 MB
  const size_t needW = (size_t)OUT_F * KDIM * 2;  // 18.9 MB
  const size_t sliceB = (size_t)SLICE_ELEMS * 4;  // 16.8 MB
  if (ws_size < needA + needW) {
    kan_fallback<<<NROWS, 256, 0, stream>>>(x, bw, bb, sw, out);
    return;
  }
  __hip_bfloat16* A = (__hip_bfloat16*)d_ws;
  __hip_bfloat16* W = (__hip_bfloat16*)((char*)d_ws + needA);
  float* P = (float*)((char*)d_ws + needA + needW);
  const bool split3 = (ws_size - needA - needW) >= 3 * sliceB;

  prep_all_kernel<<<PREP_BLOCKS + WCONV_BLOCKS, 256, 0, stream>>>(x, bw, sw, A, W);
  if (split3) {
    // 768 blocks = 3 blocks/CU, barrier-free; partials then bias-add reduce.
    gemm_kernel<96><<<dim3(NROWS / 128, OUT_F / 128, 3), 256, 0, stream>>>(A, W, P, bb, 0);
    reduce_kernel<<<SLICE_ELEMS / (4 * 256), 256, 0, stream>>>(P, bb, out, 3);
  } else {
    gemm_kernel<288><<<dim3(NROWS / 128, OUT_F / 128, 1), 256, 0, stream>>>(A, W, out, bb, 1);
  }
}

// Round 9
// 280.638 us; speedup vs baseline: 1.3709x; 1.3709x over previous
//
#include <hip/hip_runtime.h>
#include <hip/hip_bf16.h>
#include <stdint.h>

#define IN_F 1024
#define OUT_F 1024
#define NB 8
#define KDIM (IN_F + IN_F * NB)  /* 9216 */
#define NROWS 4096
#define SLICE_ELEMS (NROWS * OUT_F)
#define PREP_BLOCKS ((NROWS * IN_F) / 256)        /* 16384 */
#define WCONV_BLOCKS ((OUT_F * KDIM) / (4 * 256)) /* 9216  */
#define SPLIT 4
#define KSLICE (KDIM / SPLIT) /* 2304 */

typedef __attribute__((ext_vector_type(8))) short bf16x8;
typedef __attribute__((ext_vector_type(4))) short bf16x4;
typedef __attribute__((ext_vector_type(4))) float f32x4;

// Closed-form uniform cubic B-spline (knots t_j = -2.2 + 0.4j; EPS=1e-8 shift is
// far below bf16 rounding). For x in [t_i,t_{i+1}): 4 nonzero cardinal cubics.
__device__ __forceinline__ void bspline8(float x, float b8[8]) {
  float u = (x + 2.2f) * 2.5f;  // (x - t0)/h
  bool in = (u >= 0.0f) && (u < 11.0f);
  float uc = fminf(fmaxf(u, 0.0f), 10.99f);
  int i = (int)uc;
  float f = uc - (float)i;
  float g = 1.0f - f;
  float f2 = f * f, f3 = f2 * f;
  const float s = 1.0f / 6.0f;
  float v0 = f3 * s;
  float v1 = (-3.0f * f3 + 3.0f * f2 + 3.0f * f + 1.0f) * s;
  float v2 = (3.0f * f3 - 6.0f * f2 + 4.0f) * s;
  float v3 = g * g * g * s;
#pragma unroll
  for (int j = 0; j < 8; ++j) {
    int d = i - j;
    float r = (d == 0) ? v0 : (d == 1) ? v1 : (d == 2) ? v2 : (d == 3) ? v3 : 0.0f;
    b8[j] = in ? r : 0.0f;
  }
}

// A := [silu(x) | bspline(x)] bf16, W := [bw | sw] bf16. One launch, branch on blockIdx.
__global__ void prep_all_kernel(const float* __restrict__ x, const float* __restrict__ bw,
                                const float* __restrict__ sw, __hip_bfloat16* __restrict__ A,
                                __hip_bfloat16* __restrict__ W) {
  if (blockIdx.x < PREP_BLOCKS) {
    int idx = blockIdx.x * 256 + threadIdx.x;
    int n = idx >> 10;
    int i = idx & 1023;
    float xv = x[idx];
    float sl = xv / (1.0f + __expf(-xv));
    __hip_bfloat16* row = A + (size_t)n * KDIM;
    row[i] = __float2bfloat16(sl);
    float b8[8];
    bspline8(xv, b8);
    alignas(16) __hip_bfloat16 tmp[8];
#pragma unroll
    for (int c = 0; c < 8; ++c) tmp[c] = __float2bfloat16(b8[c]);
    *(bf16x8*)(row + IN_F + i * 8) = *(const bf16x8*)tmp;
  } else {
    int v = (blockIdx.x - PREP_BLOCKS) * 256 + threadIdx.x;
    int e = v * 4;
    int o = e / KDIM;
    int k = e - o * KDIM;
    float4 val = (k < IN_F) ? *(const float4*)(bw + o * IN_F + k)
                            : *(const float4*)(sw + (size_t)o * (IN_F * NB) + (k - IN_F));
    alignas(8) __hip_bfloat16 t[4];
    t[0] = __float2bfloat16(val.x);
    t[1] = __float2bfloat16(val.y);
    t[2] = __float2bfloat16(val.z);
    t[3] = __float2bfloat16(val.w);
    *(bf16x4*)(W + e) = *(const bf16x4*)t;
  }
}

// dst[z] = A[4096,9216] @ W[1024,9216]^T over K-slice z. 128x128 tile, BK=32,
// double-buffered LDS (32 KB). This is round-4's kernel (the best measured GEMM,
// VGPR 72, conflict-free layout) with split-K=4 -> grid 32x8x4 = 1024 blocks =
// 4 blocks/CU and PLAIN stores to a partials buffer (round-7's atomics poisoned
// the 4-blk/CU experiment; this isolates TLP as the only variable vs round 4).
// LDS layout per buffer: 8 groups of 16 rows; group g at [g*512,(g+1)*512) bf16
// in MFMA fragment order (lane l: row=l&15, kchunk=l>>4) -> every ds/staging
// addr = wave-uniform base + 16B*lane: conflict-free; legal global_load_lds.
__global__ __launch_bounds__(256) void gemm_kernel(const __hip_bfloat16* __restrict__ A,
                                                   const __hip_bfloat16* __restrict__ W,
                                                   float* __restrict__ dst) {
  __shared__ __hip_bfloat16 lA[2][128 * 32];
  __shared__ __hip_bfloat16 lB[2][128 * 32];
  const int tid = threadIdx.x;
  const int wave = tid >> 6;
  const int lane = tid & 63;
  const int bm = blockIdx.x * 128;
  const int bn = blockIdx.y * 128;
  const int kbeg = blockIdx.z * KSLICE;
  const int iters = KSLICE / 32;    // 72
  const int srow = lane & 15;       // staging row within a 16-row group
  const int skc = (lane >> 4) * 8;  // staging k-chunk offset (elements)
  const int wm = (wave & 1) * 64;
  const int wn = (wave >> 1) * 64;
  const int r = lane & 15;
  const int quad = lane >> 4;

  const int g0 = wave * 2;  // this wave stages row-groups g0, g0+1 of A and B
  const __hip_bfloat16* gA0 = A + (size_t)(bm + g0 * 16 + srow) * KDIM + kbeg + skc;
  const __hip_bfloat16* gA1 = gA0 + (size_t)16 * KDIM;
  const __hip_bfloat16* gB0 = W + (size_t)(bn + g0 * 16 + srow) * KDIM + kbeg + skc;
  const __hip_bfloat16* gB1 = gB0 + (size_t)16 * KDIM;
  const int o0 = g0 * 512;  // wave-uniform LDS offsets
  const int o1 = o0 + 512;

  f32x4 acc[4][4];
#pragma unroll
  for (int a = 0; a < 4; ++a)
#pragma unroll
    for (int b = 0; b < 4; ++b) acc[a][b] = (f32x4){0.f, 0.f, 0.f, 0.f};

#define STAGE(IT, BUF)                                                                            \
  do {                                                                                            \
    const int koff = (IT)*32;                                                                     \
    __builtin_amdgcn_global_load_lds((const __attribute__((address_space(1))) void*)(gA0 + koff), \
                                     (__attribute__((address_space(3))) void*)(lA[BUF] + o0), 16, \
                                     0, 0);                                                       \
    __builtin_amdgcn_global_load_lds((const __attribute__((address_space(1))) void*)(gA1 + koff), \
                                     (__attribute__((address_space(3))) void*)(lA[BUF] + o1), 16, \
                                     0, 0);                                                       \
    __builtin_amdgcn_global_load_lds((const __attribute__((address_space(1))) void*)(gB0 + koff), \
                                     (__attribute__((address_space(3))) void*)(lB[BUF] + o0), 16, \
                                     0, 0);                                                       \
    __builtin_amdgcn_global_load_lds((const __attribute__((address_space(1))) void*)(gB1 + koff), \
                                     (__attribute__((address_space(3))) void*)(lB[BUF] + o1), 16, \
                                     0, 0);                                                       \
  } while (0)

  STAGE(0, 0);
  __syncthreads();

  for (int it = 0; it < iters; ++it) {
    const int p = it & 1;
    if (it + 1 < iters) STAGE(it + 1, p ^ 1);  // in flight across the compute phase

    bf16x8 af[4], bfr[4];
#pragma unroll
    for (int t = 0; t < 4; ++t) {
      af[t] = *(const bf16x8*)&lA[p][((wm >> 4) + t) * 512 + lane * 8];
      bfr[t] = *(const bf16x8*)&lB[p][((wn >> 4) + t) * 512 + lane * 8];
    }
#pragma unroll
    for (int tm = 0; tm < 4; ++tm)
#pragma unroll
      for (int tn = 0; tn < 4; ++tn)
        acc[tm][tn] =
            __builtin_amdgcn_mfma_f32_16x16x32_bf16(af[tm], bfr[tn], acc[tm][tn], 0, 0, 0);

    __syncthreads();  // drains vmcnt (tile it+1 staged) + all waves done reading buf p
  }
#undef STAGE

  // C/D map: col=lane&15, row=quad*4+reg (m89-verified). Plain stores, no atomics.
  float* __restrict__ d = dst + (size_t)blockIdx.z * SLICE_ELEMS;
#pragma unroll
  for (int tm = 0; tm < 4; ++tm) {
#pragma unroll
    for (int tn = 0; tn < 4; ++tn) {
      const int col = bn + wn + tn * 16 + r;
#pragma unroll
      for (int reg = 0; reg < 4; ++reg) {
        const int rowi = bm + wm + tm * 16 + quad * 4 + reg;
        d[(size_t)rowi * OUT_F + col] = acc[tm][tn][reg];
      }
    }
  }
}

// out = bias + sum_s P[s], float4 per thread.
__global__ void reduce_kernel(const float* __restrict__ P, const float* __restrict__ bias,
                              float* __restrict__ out, int S) {
  int v = blockIdx.x * 256 + threadIdx.x;
  int e = v * 4;
  int o = e & (OUT_F - 1);
  float4 acc = *(const float4*)(bias + o);
  for (int s = 0; s < S; ++s) {
    float4 p = *(const float4*)(P + (size_t)s * SLICE_ELEMS + e);
    acc.x += p.x;
    acc.y += p.y;
    acc.z += p.z;
    acc.w += p.w;
  }
  *(float4*)(out + e) = acc;
}

// Single-slice variant with fused bias (used only if ws can't hold P).
__global__ __launch_bounds__(256) void gemm1_bias(const __hip_bfloat16* __restrict__ A,
                                                  const __hip_bfloat16* __restrict__ W,
                                                  const float* __restrict__ bias,
                                                  float* __restrict__ out) {
  // Thin wrapper logic duplicated from gemm_kernel with z=0, kslice=KDIM, +bias.
  __shared__ __hip_bfloat16 lA[2][128 * 32];
  __shared__ __hip_bfloat16 lB[2][128 * 32];
  const int tid = threadIdx.x;
  const int wave = tid >> 6;
  const int lane = tid & 63;
  const int bm = blockIdx.x * 128;
  const int bn = blockIdx.y * 128;
  const int srow = lane & 15;
  const int skc = (lane >> 4) * 8;
  const int wm = (wave & 1) * 64;
  const int wn = (wave >> 1) * 64;
  const int r = lane & 15;
  const int quad = lane >> 4;
  const int g0 = wave * 2;
  const __hip_bfloat16* gA0 = A + (size_t)(bm + g0 * 16 + srow) * KDIM + skc;
  const __hip_bfloat16* gA1 = gA0 + (size_t)16 * KDIM;
  const __hip_bfloat16* gB0 = W + (size_t)(bn + g0 * 16 + srow) * KDIM + skc;
  const __hip_bfloat16* gB1 = gB0 + (size_t)16 * KDIM;
  const int o0 = g0 * 512, o1 = o0 + 512;
  f32x4 acc[4][4];
#pragma unroll
  for (int a = 0; a < 4; ++a)
#pragma unroll
    for (int b = 0; b < 4; ++b) acc[a][b] = (f32x4){0.f, 0.f, 0.f, 0.f};
#define STAGE1(IT, BUF)                                                                           \
  do {                                                                                            \
    const int koff = (IT)*32;                                                                     \
    __builtin_amdgcn_global_load_lds((const __attribute__((address_space(1))) void*)(gA0 + koff), \
                                     (__attribute__((address_space(3))) void*)(lA[BUF] + o0), 16, \
                                     0, 0);                                                       \
    __builtin_amdgcn_global_load_lds((const __attribute__((address_space(1))) void*)(gA1 + koff), \
                                     (__attribute__((address_space(3))) void*)(lA[BUF] + o1), 16, \
                                     0, 0);                                                       \
    __builtin_amdgcn_global_load_lds((const __attribute__((address_space(1))) void*)(gB0 + koff), \
                                     (__attribute__((address_space(3))) void*)(lB[BUF] + o0), 16, \
                                     0, 0);                                                       \
    __builtin_amdgcn_global_load_lds((const __attribute__((address_space(1))) void*)(gB1 + koff), \
                                     (__attribute__((address_space(3))) void*)(lB[BUF] + o1), 16, \
                                     0, 0);                                                       \
  } while (0)
  STAGE1(0, 0);
  __syncthreads();
  for (int it = 0; it < KDIM / 32; ++it) {
    const int p = it & 1;
    if (it + 1 < KDIM / 32) STAGE1(it + 1, p ^ 1);
    bf16x8 af[4], bfr[4];
#pragma unroll
    for (int t = 0; t < 4; ++t) {
      af[t] = *(const bf16x8*)&lA[p][((wm >> 4) + t) * 512 + lane * 8];
      bfr[t] = *(const bf16x8*)&lB[p][((wn >> 4) + t) * 512 + lane * 8];
    }
#pragma unroll
    for (int tm = 0; tm < 4; ++tm)
#pragma unroll
      for (int tn = 0; tn < 4; ++tn)
        acc[tm][tn] =
            __builtin_amdgcn_mfma_f32_16x16x32_bf16(af[tm], bfr[tn], acc[tm][tn], 0, 0, 0);
    __syncthreads();
  }
#undef STAGE1
#pragma unroll
  for (int tm = 0; tm < 4; ++tm) {
#pragma unroll
    for (int tn = 0; tn < 4; ++tn) {
      const int col = bn + wn + tn * 16 + r;
      const float bv = bias[col];
#pragma unroll
      for (int reg = 0; reg < 4; ++reg) {
        const int rowi = bm + wm + tm * 16 + quad * 4 + reg;
        out[(size_t)rowi * OUT_F + col] = acc[tm][tn][reg] + bv;
      }
    }
  }
}

// Emergency fallback if ws is too small for A+W (fp32, slow but correct).
__global__ void kan_fallback(const float* __restrict__ x, const float* __restrict__ bw,
                             const float* __restrict__ bb, const float* __restrict__ sw,
                             float* __restrict__ out) {
  __shared__ float act[KDIM];
  int n = blockIdx.x;
  for (int i = threadIdx.x; i < IN_F; i += 256) {
    float xv = x[(size_t)n * IN_F + i];
    act[i] = xv / (1.0f + __expf(-xv));
    float b8[8];
    bspline8(xv, b8);
#pragma unroll
    for (int c = 0; c < 8; ++c) act[IN_F + i * 8 + c] = b8[c];
  }
  __syncthreads();
  for (int o = threadIdx.x; o < OUT_F; o += 256) {
    float s = bb[o];
    const float* wbp = bw + (size_t)o * IN_F;
    for (int k = 0; k < IN_F; ++k) s += act[k] * wbp[k];
    const float* wsp = sw + (size_t)o * (IN_F * NB);
    for (int k = 0; k < IN_F * NB; ++k) s += act[IN_F + k] * wsp[k];
    out[(size_t)n * OUT_F + o] = s;
  }
}

extern "C" void kernel_launch(void* const* d_in, const int* in_sizes, int n_in, void* d_out,
                              int out_size, void* d_ws, size_t ws_size, hipStream_t stream) {
  const float* x = (const float*)d_in[0];
  const float* bw = (const float*)d_in[1];
  const float* bb = (const float*)d_in[2];
  const float* sw = (const float*)d_in[3];
  float* out = (float*)d_out;

  const size_t needA = (size_t)NROWS * KDIM * 2;  // 75.5 MB
  const size_t needW = (size_t)OUT_F * KDIM * 2;  // 18.9 MB
  const size_t sliceB = (size_t)SLICE_ELEMS * 4;  // 16.8 MB
  if (ws_size < needA + needW) {
    kan_fallback<<<NROWS, 256, 0, stream>>>(x, bw, bb, sw, out);
    return;
  }
  __hip_bfloat16* A = (__hip_bfloat16*)d_ws;
  __hip_bfloat16* W = (__hip_bfloat16*)((char*)d_ws + needA);
  float* P = (float*)((char*)d_ws + needA + needW);
  const bool splitok = (ws_size - needA - needW) >= SPLIT * sliceB;

  prep_all_kernel<<<PREP_BLOCKS + WCONV_BLOCKS, 256, 0, stream>>>(x, bw, sw, A, W);
  if (splitok) {
    gemm_kernel<<<dim3(NROWS / 128, OUT_F / 128, SPLIT), 256, 0, stream>>>(A, W, P);
    reduce_kernel<<<SLICE_ELEMS / (4 * 256), 256, 0, stream>>>(P, bb, out, SPLIT);
  } else {
    gemm1_bias<<<dim3(NROWS / 128, OUT_F / 128), 256, 0, stream>>>(A, W, bb, out);
  }
}